// Round 10
// baseline (23.991 us; speedup 1.0000x reference)
//
#include <hip/hip_runtime.h>
#include <hip/hip_bf16.h>

// Problem constants (from reference)
#define T_LEN 2048
#define D_DIM 64
#define K_CH  8
#define B_SZ  8

// Hierarchical chunked scan: CT=32 -> NC=64 chunks, 512 (b,c) blocks.
#define CT 32
#define NC (T_LEN / CT)        // 64
#define NBLK (B_SZ * NC)       // 512

__device__ __forceinline__ float2 cmul(float2 a, float2 b) {
    return make_float2(a.x * b.x - a.y * b.y, a.x * b.y + a.y * b.x);
}
__device__ __forceinline__ float2 cadd(float2 a, float2 b) {
    return make_float2(a.x + b.x, a.y + b.y);
}

// Kernel 1: chunk-local aggregate S_c = sum_j A^{CT-1-j} h[j] (zero init),
// even/odd A^2 chains for ILP. 512 threads = k(8) x d(64). Coalesced.
__global__ __launch_bounds__(512, 4) void s4d_carry(
    const float* __restrict__ h,
    const float* __restrict__ log_neg_re,
    const float* __restrict__ imag,
    const float* __restrict__ log_dt,
    float2* __restrict__ carries)   // [B][NC][K][D]
{
    const int b = blockIdx.x >> 6;
    const int c = blockIdx.x & 63;
    const int tid = threadIdx.x;
    const int k = tid >> 6;         // wave-uniform
    const int d = tid & 63;

    const float dt = expf(log_dt[0]);
    const float re = -expf(log_neg_re[k]);
    const float im = imag[k];
    const float mag = expf(re * dt);
    const float2 A  = make_float2(mag * cosf(im * dt), mag * sinf(im * dt));
    const float2 A2 = cmul(A, A);

    const float* hp = h + ((size_t)b * T_LEN + (size_t)c * CT) * D_DIM + d;

    float2 se = {0.f, 0.f}, so = {0.f, 0.f};
    #pragma unroll
    for (int m = 0; m < CT / 2; ++m) {
        float he = hp[(size_t)(2 * m) * D_DIM];       // 256B/wave
        float ho = hp[(size_t)(2 * m + 1) * D_DIM];
        se = cmul(A2, se); se.x += he;
        so = cmul(A2, so); so.x += ho;
    }
    const float2 S = cadd(cmul(A, se), so);

    carries[((size_t)(b * NC + c) * K_CH + k) * D_DIM + d] = S;
}

// Kernel 2 (tiny): per (b,k), one wave of 64 d-lanes. Load ALL 64 chunk
// aggregates upfront (overlapped in the memory pipe — R9-proven), Horner-scan
// with Act=A^CT, store the inclusive prefixes P_c = sum_{j<=c} Act^{c-j} S_j.
// Only 64 waves total; VGPR-heavy is fine here.
__global__ void s4d_scan(
    const float* __restrict__ log_neg_re,
    const float* __restrict__ imag,
    const float* __restrict__ log_dt,
    const float2* __restrict__ carries,
    float2* __restrict__ P)         // [B][NC][K][D]
{
    const int b = blockIdx.x >> 3;
    const int k = blockIdx.x & 7;
    const int d = threadIdx.x;      // 0..63

    const float dt = expf(log_dt[0]);
    const float re = -expf(log_neg_re[k]);
    const float im = imag[k];
    const float magC = expf(re * dt * (float)CT);
    const float angC = im * dt * (float)CT;
    const float2 Act = make_float2(magC * cosf(angC), magC * sinf(angC));

    const size_t cs = (size_t)K_CH * D_DIM;
    const float2* cp = carries + ((size_t)(b * NC) * K_CH + (size_t)k) * D_DIM + d;
    float2* pp = P + ((size_t)(b * NC) * K_CH + (size_t)k) * D_DIM + d;

    // Issue all 64 loads upfront (static indices; one exposed round trip).
    float2 sv[NC];
    #pragma unroll
    for (int c = 0; c < NC; ++c) sv[c] = cp[(size_t)c * cs];

    float2 x = {0.f, 0.f};
    #pragma unroll
    for (int c = 0; c < NC; ++c) {
        x = cadd(cmul(Act, x), sv[c]);
        pp[(size_t)c * cs] = x;     // 512B/wave, fire-and-forget
    }
}

// Kernel 3: init = one cached load of P_{c-1} (issued before the transcendental
// constant block so its latency hides), then 32-step replay streaming h,
// coalesced 256B/wave stores. Low VGPR -> 2 blocks/CU, 16 waves/CU.
__global__ __launch_bounds__(512, 4) void s4d_out(
    const float* __restrict__ h,
    const float* __restrict__ log_neg_re,
    const float* __restrict__ imag,
    const float* __restrict__ B_proj,
    const float* __restrict__ log_dt,
    const float2* __restrict__ P,
    float* __restrict__ out)
{
    const int b = blockIdx.x >> 6;
    const int c = blockIdx.x & 63;
    const int tid = threadIdx.x;
    const int k = tid >> 6;
    const int d = tid & 63;

    // Issue the init load FIRST — hides under the expf/cosf below.
    float2 x = {0.f, 0.f};
    if (c > 0)
        x = P[((size_t)(b * NC + (c - 1)) * K_CH + k) * D_DIM + d];

    const float dt = expf(log_dt[0]);
    const float re = -expf(log_neg_re[k]);
    const float im = imag[k];
    const float mag = expf(re * dt);
    const float2 A = make_float2(mag * cosf(im * dt), mag * sinf(im * dt));

    // C2 = 2 * B_proj * (A-1)/eig
    const float inv = 1.f / (re * re + im * im);
    const float2 num = make_float2(A.x - 1.f, A.y);
    const float bp = B_proj[k];
    const float2 C2v = make_float2(2.f * bp * (num.x * re + num.y * im) * inv,
                                   2.f * bp * (num.y * re - num.x * im) * inv);

    const float* hp = h + ((size_t)b * T_LEN + (size_t)c * CT) * D_DIM + d;
    float* op = out + (((size_t)b * T_LEN + (size_t)c * CT) * K_CH + k) * D_DIM + d;

    #pragma unroll 8
    for (int t = 0; t < CT; ++t) {
        float hv = hp[(size_t)t * D_DIM];
        x = cmul(A, x);
        x.x += hv;
        op[(size_t)t * (K_CH * D_DIM)] = C2v.x * x.x - C2v.y * x.y;
    }
}

extern "C" void kernel_launch(void* const* d_in, const int* in_sizes, int n_in,
                              void* d_out, int out_size, void* d_ws, size_t ws_size,
                              hipStream_t stream) {
    const float* h          = (const float*)d_in[0];
    const float* log_neg_re = (const float*)d_in[1];
    const float* imag       = (const float*)d_in[2];
    const float* B_proj     = (const float*)d_in[3];
    const float* log_dt     = (const float*)d_in[4];
    float* out = (float*)d_out;

    // d_ws: [0, 2MB) carries, [2MB, 4MB) prefixes
    float2* carries = (float2*)d_ws;
    float2* P       = (float2*)((char*)d_ws + (2u << 20));

    hipLaunchKernelGGL(s4d_carry, dim3(NBLK), dim3(512), 0, stream,
                       h, log_neg_re, imag, log_dt, carries);
    hipLaunchKernelGGL(s4d_scan, dim3(B_SZ * K_CH), dim3(64), 0, stream,
                       log_neg_re, imag, log_dt, carries, P);
    hipLaunchKernelGGL(s4d_out, dim3(NBLK), dim3(512), 0, stream,
                       h, log_neg_re, imag, B_proj, log_dt, P, out);
}

// Round 11
// 22.248 us; speedup vs baseline: 1.0783x; 1.0783x over previous
//
#include <hip/hip_runtime.h>
#include <hip/hip_bf16.h>

// Problem constants (from reference)
#define T_LEN 2048
#define D_DIM 64
#define K_CH  8
#define B_SZ  8

// k1: CT=64 chunks (NC64=32, 256 blocks). Writes full-chunk carry AND
//     mid-chunk (32-step) carry — the latter is free (running state at m=16).
// k2: CT=32 output chunks (NC32=64, 512 blocks = 2/CU, 16 waves/CU).
#define CT64 64
#define NC64 (T_LEN / CT64)    // 32
#define CT32 32
#define NC32 (T_LEN / CT32)    // 64

__device__ __forceinline__ float2 cmul(float2 a, float2 b) {
    return make_float2(a.x * b.x - a.y * b.y, a.x * b.y + a.y * b.x);
}
__device__ __forceinline__ float2 cadd(float2 a, float2 b) {
    return make_float2(a.x + b.x, a.y + b.y);
}

// Kernel 1: per (b, c64, k, d): S_full = sum_{j<64} A^{63-j} h[j]  (zero init)
// and S_half = sum_{j<32} A^{31-j} h[j]. Even/odd A^2 chains for ILP.
__global__ __launch_bounds__(512) void s4d_carry(
    const float* __restrict__ h,
    const float* __restrict__ log_neg_re,
    const float* __restrict__ imag,
    const float* __restrict__ log_dt,
    float2* __restrict__ carry_full,   // [B][NC64][K][D]
    float2* __restrict__ carry_half)   // [B][NC64][K][D]
{
    const int bid = blockIdx.x;
    const int b = bid >> 5;            // NC64 = 32
    const int c = bid & 31;
    const int tid = threadIdx.x;
    const int k = tid >> 6;            // wave-uniform
    const int d = tid & 63;

    const float dt = expf(log_dt[0]);
    const float re = -expf(log_neg_re[k]);
    const float im = imag[k];
    const float mag = expf(re * dt);
    const float2 A  = make_float2(mag * cosf(im * dt), mag * sinf(im * dt));
    const float2 A2 = cmul(A, A);

    const float* hp = h + ((size_t)b * T_LEN + (size_t)c * CT64) * D_DIM + d;

    float2 se = {0.f, 0.f}, so = {0.f, 0.f};
    #pragma unroll
    for (int m = 0; m < 16; ++m) {     // first 32 steps
        float he = hp[(size_t)(2 * m) * D_DIM];        // 256B/wave
        float ho = hp[(size_t)(2 * m + 1) * D_DIM];
        se = cmul(A2, se); se.x += he;
        so = cmul(A2, so); so.x += ho;
    }
    const float2 S_half = cadd(cmul(A, se), so);
    #pragma unroll
    for (int m = 16; m < 32; ++m) {    // remaining 32 steps
        float he = hp[(size_t)(2 * m) * D_DIM];
        float ho = hp[(size_t)(2 * m + 1) * D_DIM];
        se = cmul(A2, se); se.x += he;
        so = cmul(A2, so); so.x += ho;
    }
    const float2 S_full = cadd(cmul(A, se), so);

    const size_t idx = ((size_t)(b * NC64 + c) * K_CH + k) * D_DIM + d;
    carry_half[idx] = S_half;
    carry_full[idx] = S_full;
}

// Kernel 2: 512 blocks, chunk c32 = 2m+odd. Issue all combine loads FIRST
// (latency hides under the transcendental constant block), Horner over the
// m full carries with Act64, one Act32+S_half step if odd, then 32-step
// replay streaming h with coalesced 256B/wave stores.
__global__ __launch_bounds__(512, 4) void s4d_out(
    const float* __restrict__ h,
    const float* __restrict__ log_neg_re,
    const float* __restrict__ imag,
    const float* __restrict__ B_proj,
    const float* __restrict__ log_dt,
    const float2* __restrict__ carry_full,
    const float2* __restrict__ carry_half,
    float* __restrict__ out)
{
    const int bid = blockIdx.x;
    const int b = bid >> 6;            // NC32 = 64
    const int c32 = bid & 63;
    const int m = c32 >> 1;            // block-uniform
    const int odd = c32 & 1;
    const int tid = threadIdx.x;
    const int k = tid >> 6;
    const int d = tid & 63;

    // ---- issue all combine loads first (no dependence on constants) ----
    const size_t cs = (size_t)K_CH * D_DIM;
    const float2* cpf = carry_full + ((size_t)(b * NC64) * K_CH + (size_t)k) * D_DIM + d;
    float2 sv[NC64 - 1];
    #pragma unroll
    for (int j = 0; j < NC64 - 1; ++j)   // uniform guard, static index
        sv[j] = (j < m) ? cpf[(size_t)j * cs] : make_float2(0.f, 0.f);
    float2 sh = make_float2(0.f, 0.f);
    if (odd)
        sh = carry_half[((size_t)(b * NC64 + m) * K_CH + k) * D_DIM + d];

    // ---- constants (loads in flight above this) ----
    const float dt = expf(log_dt[0]);
    const float re = -expf(log_neg_re[k]);
    const float im = imag[k];
    const float mag = expf(re * dt);
    const float2 A = make_float2(mag * cosf(im * dt), mag * sinf(im * dt));

    const float mag32 = expf(re * dt * 32.f);
    const float ang32 = im * dt * 32.f;
    const float2 Act32 = make_float2(mag32 * cosf(ang32), mag32 * sinf(ang32));
    const float2 Act64 = cmul(Act32, Act32);

    // C2 = 2 * B_proj * (A-1)/eig
    const float inv = 1.f / (re * re + im * im);
    const float2 num = make_float2(A.x - 1.f, A.y);
    const float bp = B_proj[k];
    const float2 C2v = make_float2(2.f * bp * (num.x * re + num.y * im) * inv,
                                   2.f * bp * (num.y * re - num.x * im) * inv);

    // ---- Horner combine: x = sum_{j<m} Act64^{m-1-j} sv[j] ----
    float2 x = {0.f, 0.f};
    #pragma unroll
    for (int j = 0; j < NC64 - 1; ++j)
        if (j < m) x = cadd(cmul(Act64, x), sv[j]);
    if (odd) x = cadd(cmul(Act32, x), sh);   // advance to mid-chunk state

    // ---- replay 32 steps, coalesced stores ----
    const float* hp = h + ((size_t)b * T_LEN + (size_t)c32 * CT32) * D_DIM + d;
    float* op = out + (((size_t)b * T_LEN + (size_t)c32 * CT32) * K_CH + k) * D_DIM + d;

    #pragma unroll 8
    for (int t = 0; t < CT32; ++t) {
        float hv = hp[(size_t)t * D_DIM];
        x = cmul(A, x);
        x.x += hv;
        op[(size_t)t * (K_CH * D_DIM)] = C2v.x * x.x - C2v.y * x.y;
    }
}

extern "C" void kernel_launch(void* const* d_in, const int* in_sizes, int n_in,
                              void* d_out, int out_size, void* d_ws, size_t ws_size,
                              hipStream_t stream) {
    const float* h          = (const float*)d_in[0];
    const float* log_neg_re = (const float*)d_in[1];
    const float* imag       = (const float*)d_in[2];
    const float* B_proj     = (const float*)d_in[3];
    const float* log_dt     = (const float*)d_in[4];
    float* out = (float*)d_out;

    // d_ws: [0, 1MB) carry_full, [1MB, 2MB) carry_half
    float2* carry_full = (float2*)d_ws;
    float2* carry_half = (float2*)((char*)d_ws + (1u << 20));

    hipLaunchKernelGGL(s4d_carry, dim3(B_SZ * NC64), dim3(512), 0, stream,
                       h, log_neg_re, imag, log_dt, carry_full, carry_half);
    hipLaunchKernelGGL(s4d_out, dim3(B_SZ * NC32), dim3(512), 0, stream,
                       h, log_neg_re, imag, B_proj, log_dt,
                       carry_full, carry_half, out);
}

// Round 12
// 21.952 us; speedup vs baseline: 1.0929x; 1.0135x over previous
//
#include <hip/hip_runtime.h>
#include <hip/hip_bf16.h>

// Problem constants (from reference)
#define T_LEN 2048
#define D_DIM 64
#define K_CH  8
#define B_SZ  8

// k1: CT=64 chunks (NC=32, 256 blocks), writes full-chunk AND mid-chunk carry.
// k2: 256 blocks, 512 thr = 2 halves x (8 k x 32 d-pairs); float2/float4 I/O.
#define CT 64
#define NC (T_LEN / CT)        // 32
#define NBLK (B_SZ * NC)       // 256

__device__ __forceinline__ float2 cmul(float2 a, float2 b) {
    return make_float2(a.x * b.x - a.y * b.y, a.x * b.y + a.y * b.x);
}
__device__ __forceinline__ float2 cadd(float2 a, float2 b) {
    return make_float2(a.x + b.x, a.y + b.y);
}

// Kernel 1: per (b,c,k,d): S_half = sum_{j<32} A^{31-j} h[j],
//                          S_full = sum_{j<64} A^{63-j} h[j]. (zero init)
__global__ __launch_bounds__(512) void s4d_carry(
    const float* __restrict__ h,
    const float* __restrict__ log_neg_re,
    const float* __restrict__ imag,
    const float* __restrict__ log_dt,
    float2* __restrict__ carry_full,   // [B][NC][K][D]
    float2* __restrict__ carry_half)   // [B][NC][K][D]
{
    const int bid = blockIdx.x;
    const int b = bid >> 5;            // NC = 32
    const int c = bid & 31;
    const int tid = threadIdx.x;
    const int k = tid >> 6;            // wave-uniform
    const int d = tid & 63;

    const float dt = expf(log_dt[0]);
    const float re = -expf(log_neg_re[k]);
    const float im = imag[k];
    const float mag = expf(re * dt);
    const float2 A  = make_float2(mag * cosf(im * dt), mag * sinf(im * dt));
    const float2 A2 = cmul(A, A);

    const float* hp = h + ((size_t)b * T_LEN + (size_t)c * CT) * D_DIM + d;

    float2 se = {0.f, 0.f}, so = {0.f, 0.f};
    #pragma unroll
    for (int m = 0; m < 16; ++m) {     // first 32 timesteps
        float he = hp[(size_t)(2 * m) * D_DIM];        // 256B/wave
        float ho = hp[(size_t)(2 * m + 1) * D_DIM];
        se = cmul(A2, se); se.x += he;
        so = cmul(A2, so); so.x += ho;
    }
    const float2 S_half = cadd(cmul(A, se), so);
    #pragma unroll
    for (int m = 16; m < 32; ++m) {    // remaining 32 timesteps
        float he = hp[(size_t)(2 * m) * D_DIM];
        float ho = hp[(size_t)(2 * m + 1) * D_DIM];
        se = cmul(A2, se); se.x += he;
        so = cmul(A2, so); so.x += ho;
    }
    const float2 S_full = cadd(cmul(A, se), so);

    const size_t idx = ((size_t)(b * NC + c) * K_CH + k) * D_DIM + d;
    carry_half[idx] = S_half;
    carry_full[idx] = S_full;
}

// Kernel 2: block (b,c) covers the CT=64 chunk with two independent halves.
//  half 0: x_init = X = Horner_{j<c}(Act64, S_full_j); replay t=0..31
//  half 1: x_init = Act32*X + S_half_c;                replay t=32..63
// Each thread owns 2 adjacent d's: float4 carry loads, float2 h loads,
// float2 stores (512B/wave). All combine loads issued before the
// transcendental constant block (latency hidden).
__global__ __launch_bounds__(512) void s4d_out(
    const float* __restrict__ h,
    const float* __restrict__ log_neg_re,
    const float* __restrict__ imag,
    const float* __restrict__ B_proj,
    const float* __restrict__ log_dt,
    const float2* __restrict__ carry_full,
    const float2* __restrict__ carry_half,
    float* __restrict__ out)
{
    const int bid = blockIdx.x;
    const int b = bid >> 5;            // NC = 32
    const int c = bid & 31;            // block-uniform
    const int tid = threadIdx.x;
    const int half = tid >> 8;         // wave-uniform (waves 0-3 / 4-7)
    const int t8 = tid & 255;
    const int k = t8 >> 5;             // wave spans 2 k's
    const int d2 = t8 & 31;            // float2 pair index (d = 2*d2, 2*d2+1)

    // ---- issue all combine loads first ----
    const size_t cs4 = (size_t)K_CH * D_DIM / 2;   // float4 stride per chunk
    const float4* cpf = (const float4*)(carry_full
                        + ((size_t)(b * NC) * K_CH + (size_t)k) * D_DIM) + d2;
    float4 sv[NC - 1];
    #pragma unroll
    for (int j = 0; j < NC - 1; ++j)   // uniform guard, static index
        sv[j] = (j < c) ? cpf[(size_t)j * cs4]
                        : make_float4(0.f, 0.f, 0.f, 0.f);
    float4 shv = make_float4(0.f, 0.f, 0.f, 0.f);
    if (half)
        shv = ((const float4*)(carry_half
              + ((size_t)(b * NC + c) * K_CH + (size_t)k) * D_DIM))[d2];

    // ---- constants (combine loads in flight above) ----
    const float dt = expf(log_dt[0]);
    const float re = -expf(log_neg_re[k]);
    const float im = imag[k];
    const float mag = expf(re * dt);
    const float2 A = make_float2(mag * cosf(im * dt), mag * sinf(im * dt));

    const float mag32 = expf(re * dt * 32.f);
    const float ang32 = im * dt * 32.f;
    const float2 Act32 = make_float2(mag32 * cosf(ang32), mag32 * sinf(ang32));
    const float2 Act64 = cmul(Act32, Act32);

    // C2 = 2 * B_proj * (A-1)/eig
    const float inv = 1.f / (re * re + im * im);
    const float2 num = make_float2(A.x - 1.f, A.y);
    const float bp = B_proj[k];
    const float2 C2v = make_float2(2.f * bp * (num.x * re + num.y * im) * inv,
                                   2.f * bp * (num.y * re - num.x * im) * inv);

    // ---- Horner combine over full carries (both halves need X) ----
    float2 x0 = {0.f, 0.f}, x1 = {0.f, 0.f};
    #pragma unroll
    for (int j = 0; j < NC - 1; ++j) {
        if (j < c) {
            x0 = cadd(cmul(Act64, x0), make_float2(sv[j].x, sv[j].y));
            x1 = cadd(cmul(Act64, x1), make_float2(sv[j].z, sv[j].w));
        }
    }
    if (half) {                        // advance to mid-chunk state
        x0 = cadd(cmul(Act32, x0), make_float2(shv.x, shv.y));
        x1 = cadd(cmul(Act32, x1), make_float2(shv.z, shv.w));
    }

    // ---- replay 32 steps, float2 loads/stores ----
    const int t0 = c * CT + half * 32;
    const float2* hp = (const float2*)(h + ((size_t)b * T_LEN + t0) * D_DIM) + d2;
    float2* op = (float2*)(out + (((size_t)b * T_LEN + t0) * K_CH + k) * D_DIM) + d2;

    #pragma unroll 8
    for (int t = 0; t < 32; ++t) {
        float2 hv = hp[(size_t)t * (D_DIM / 2)];
        x0 = cmul(A, x0); x0.x += hv.x;
        x1 = cmul(A, x1); x1.x += hv.y;
        op[(size_t)t * (K_CH * D_DIM / 2)] =
            make_float2(C2v.x * x0.x - C2v.y * x0.y,
                        C2v.x * x1.x - C2v.y * x1.y);   // 512B/wave
    }
}

extern "C" void kernel_launch(void* const* d_in, const int* in_sizes, int n_in,
                              void* d_out, int out_size, void* d_ws, size_t ws_size,
                              hipStream_t stream) {
    const float* h          = (const float*)d_in[0];
    const float* log_neg_re = (const float*)d_in[1];
    const float* imag       = (const float*)d_in[2];
    const float* B_proj     = (const float*)d_in[3];
    const float* log_dt     = (const float*)d_in[4];
    float* out = (float*)d_out;

    // d_ws: [0, 1MB) carry_full, [1MB, 2MB) carry_half
    float2* carry_full = (float2*)d_ws;
    float2* carry_half = (float2*)((char*)d_ws + (1u << 20));

    hipLaunchKernelGGL(s4d_carry, dim3(NBLK), dim3(512), 0, stream,
                       h, log_neg_re, imag, log_dt, carry_full, carry_half);
    hipLaunchKernelGGL(s4d_out, dim3(NBLK), dim3(512), 0, stream,
                       h, log_neg_re, imag, B_proj, log_dt,
                       carry_full, carry_half, out);
}

// Round 13
// 20.196 us; speedup vs baseline: 1.1879x; 1.0869x over previous
//
#include <hip/hip_runtime.h>
#include <hip/hip_bf16.h>

// Problem constants (from reference)
#define T_LEN 2048
#define D_DIM 64
#define K_CH  8
#define B_SZ  8

// Chunked-scan config: CT=64 -> NC=32 -> 256 blocks, 512 threads. (R9 shape.)
#define CT 64
#define NC (T_LEN / CT)        // 32
#define NBLK (B_SZ * NC)       // 256

__device__ __forceinline__ float2 cmul(float2 a, float2 b) {
    return make_float2(a.x * b.x - a.y * b.y, a.x * b.y + a.y * b.x);
}
__device__ __forceinline__ float2 cadd(float2 a, float2 b) {
    return make_float2(a.x + b.x, a.y + b.y);
}

// Kernel 1: chunk-local aggregate S = sum_j A^{CT-1-j} h[j] (zero init).
// ALL 64 h loads issued upfront (1 exposed round trip, not 8), then four
// independent A^4 chains:
//   S = A^3*ch0 + A^2*ch1 + A*ch2 + ch3,  ch_i = sum_m (A^4)^{15-m} h_{4m+i}
__global__ __launch_bounds__(512) void s4d_carry(
    const float* __restrict__ h,
    const float* __restrict__ log_neg_re,
    const float* __restrict__ imag,
    const float* __restrict__ log_dt,
    float2* __restrict__ carries)   // [B][NC][K][D]
{
    const int bid = blockIdx.x;
    const int b = bid >> 5;         // NC = 32
    const int c = bid & 31;
    const int tid = threadIdx.x;
    const int k = tid >> 6;         // wave-uniform
    const int d = tid & 63;

    // ---- issue all 64 h loads first (256B/wave coalesced each) ----
    const float* hp = h + ((size_t)b * T_LEN + (size_t)c * CT) * D_DIM + d;
    float hv[CT];
    #pragma unroll
    for (int t = 0; t < CT; ++t) hv[t] = hp[(size_t)t * D_DIM];

    // ---- constants (loads in flight) ----
    const float dt = expf(log_dt[0]);
    const float re = -expf(log_neg_re[k]);
    const float im = imag[k];
    const float mag = expf(re * dt);
    const float2 A  = make_float2(mag * cosf(im * dt), mag * sinf(im * dt));
    const float2 A2 = cmul(A, A);
    const float2 A3 = cmul(A2, A);
    const float2 A4 = cmul(A2, A2);

    // ---- four independent chains over the register file ----
    float2 c0 = {0.f, 0.f}, c1 = {0.f, 0.f}, c2 = {0.f, 0.f}, c3 = {0.f, 0.f};
    #pragma unroll
    for (int m = 0; m < CT / 4; ++m) {
        c0 = cmul(A4, c0); c0.x += hv[4 * m + 0];
        c1 = cmul(A4, c1); c1.x += hv[4 * m + 1];
        c2 = cmul(A4, c2); c2.x += hv[4 * m + 2];
        c3 = cmul(A4, c3); c3.x += hv[4 * m + 3];
    }
    const float2 S = cadd(cadd(cmul(A3, c0), cmul(A2, c1)),
                          cadd(cmul(A, c2), c3));

    carries[((size_t)(b * NC + c) * K_CH + k) * D_DIM + d] = S;
}

// Kernel 2: issue 31 carry loads, then ALL 64 h loads, before anything else.
// Horner waits only on the carries (h loads stay outstanding in the in-order
// vmcnt FIFO); the replay then runs entirely from registers — zero load
// stalls between stores. ~180 VGPR < 256 -> occupancy unchanged (8 waves/CU).
__global__ __launch_bounds__(512) void s4d_out(
    const float* __restrict__ h,
    const float* __restrict__ log_neg_re,
    const float* __restrict__ imag,
    const float* __restrict__ B_proj,
    const float* __restrict__ log_dt,
    const float2* __restrict__ carries,
    float* __restrict__ out)
{
    const int bid = blockIdx.x;
    const int b = bid >> 5;
    const int c = bid & 31;          // block-uniform
    const int tid = threadIdx.x;
    const int k = tid >> 6;
    const int d = tid & 63;

    // ---- 1. issue carry loads (needed first -> issued first) ----
    const float2* cp = carries + ((size_t)(b * NC) * K_CH + (size_t)k) * D_DIM + d;
    const size_t cs = (size_t)K_CH * D_DIM;
    float2 sv[NC - 1];
    #pragma unroll
    for (int j = 0; j < NC - 1; ++j)   // uniform guard, static index
        sv[j] = (j < c) ? cp[(size_t)j * cs] : make_float2(0.f, 0.f);

    // ---- 2. issue all 64 h loads (consumed last -> issued second) ----
    const float* hp = h + ((size_t)b * T_LEN + (size_t)c * CT) * D_DIM + d;
    float hv[CT];
    #pragma unroll
    for (int t = 0; t < CT; ++t) hv[t] = hp[(size_t)t * D_DIM];

    // ---- 3. constants (95 loads in flight above) ----
    const float dt = expf(log_dt[0]);
    const float re = -expf(log_neg_re[k]);
    const float im = imag[k];
    const float mag = expf(re * dt);
    const float2 A = make_float2(mag * cosf(im * dt), mag * sinf(im * dt));

    const float magC = expf(re * dt * (float)CT);
    const float angC = im * dt * (float)CT;
    const float2 Act = make_float2(magC * cosf(angC), magC * sinf(angC));

    // C2 = 2 * B_proj * (A-1)/eig
    const float inv = 1.f / (re * re + im * im);
    const float2 num = make_float2(A.x - 1.f, A.y);
    const float bp = B_proj[k];
    const float2 C2v = make_float2(2.f * bp * (num.x * re + num.y * im) * inv,
                                   2.f * bp * (num.y * re - num.x * im) * inv);

    // ---- 4. Horner combine: x = sum_{j<c} Act^{c-1-j} sv[j] ----
    float2 x = {0.f, 0.f};
    #pragma unroll
    for (int j = 0; j < NC - 1; ++j)
        if (j < c) x = cadd(cmul(Act, x), sv[j]);

    // ---- 5. replay from registers, coalesced 256B/wave stores ----
    float* op = out + (((size_t)b * T_LEN + (size_t)c * CT) * K_CH + k) * D_DIM + d;
    #pragma unroll
    for (int t = 0; t < CT; ++t) {
        x = cmul(A, x);
        x.x += hv[t];
        op[(size_t)t * (K_CH * D_DIM)] = C2v.x * x.x - C2v.y * x.y;
    }
}

extern "C" void kernel_launch(void* const* d_in, const int* in_sizes, int n_in,
                              void* d_out, int out_size, void* d_ws, size_t ws_size,
                              hipStream_t stream) {
    const float* h          = (const float*)d_in[0];
    const float* log_neg_re = (const float*)d_in[1];
    const float* imag       = (const float*)d_in[2];
    const float* B_proj     = (const float*)d_in[3];
    const float* log_dt     = (const float*)d_in[4];
    float* out = (float*)d_out;

    float2* carries = (float2*)d_ws;   // 8*32*8*64*8B = 1 MiB

    hipLaunchKernelGGL(s4d_carry, dim3(NBLK), dim3(512), 0, stream,
                       h, log_neg_re, imag, log_dt, carries);
    hipLaunchKernelGGL(s4d_out, dim3(NBLK), dim3(512), 0, stream,
                       h, log_neg_re, imag, B_proj, log_dt, carries, out);
}